// Round 1
// baseline (1206.139 us; speedup 1.0000x reference)
//
#include <hip/hip_runtime.h>

#define NG 64
#define KK 64
#define HIDDEN 256
#define DIST 8
#define NNODES 50000
#define PTOT (NNODES*DIST)   // 400000 flattened rows
#define EPSV 0.1f
#define NITERS 20
#define STABV 1e-8f
#define CMAXV 1e6f

// workspace layout (float-element offsets)
#define OFF_AINV 0                     // 64 f32: 1/max(rows_per_graph,1)
#define OFF_COUNTS 64                  // 64 i32: nodes per graph
#define OFF_NNZ 128                    // 1 i32: number of nonzero Kmat rows
#define OFF_ROWIDX 256                 // PTOT i32
#define OFF_ROWSEG (OFF_ROWIDX + PTOT) // PTOT i32
#define OFF_UC (OFF_ROWSEG + PTOT)     // PTOT f32 (final u per compact row)
#define OFF_KROWS (OFF_UC + PTOT)      // cap*64 f32 compacted Kmat rows

__global__ __launch_bounds__(256) void init_kernel(float* ws) {
  int t = threadIdx.x;
  if (t == 0) ((int*)(ws + OFF_NNZ))[0] = 0;
  if (t < NG) ((int*)(ws + OFF_COUNTS))[t] = 0;
}

__global__ __launch_bounds__(256) void counts_kernel(const int* __restrict__ bidx,
                                                     float* ws) {
  __shared__ int h[NG];
  int t = threadIdx.x;
  if (t < NG) h[t] = 0;
  __syncthreads();
  int i = blockIdx.x * 256 + t;
  if (i < NNODES) atomicAdd(&h[bidx[i]], 1);
  __syncthreads();
  if (t < NG && h[t] > 0) atomicAdd(&((int*)(ws + OFF_COUNTS))[t], h[t]);
}

__global__ __launch_bounds__(64) void ainv_kernel(float* ws) {
  int g = threadIdx.x;
  int c = ((int*)(ws + OFF_COUNTS))[g];
  ws[OFF_AINV + g] = 1.0f / fmaxf((float)(c * DIST), 1.0f);
}

// Block = 512 threads = 8 waves; block handles 64 points; wave handles 8 points,
// lane = codebook entry. Codebook lives in LDS as float4-transposed with XOR
// swizzle: element (j,k) at cbT[(j<<6) | (k^j)] -> conflict-free ds_read_b128
// in the main loop AND conflict-free cooperative store.
__global__ __launch_bounds__(512) void cost_kernel(const float* __restrict__ x,
    const int* __restrict__ bidx, const float* __restrict__ cb,
    float* __restrict__ ws, int cap) {
  __shared__ float4 cbT[64 * 64];  // 64 KiB
  int tid = threadIdx.x;
  const float4* cb4 = (const float4*)cb;
  for (int idx = tid; idx < 4096; idx += 512) {
    int k = idx >> 6, j = idx & 63;          // consecutive tid -> coalesced cb read
    cbT[(j << 6) | (k ^ j)] = cb4[idx];      // cb4[k*64+j] = cb[k][4j..4j+3]
  }
  __syncthreads();
  int wave = tid >> 6, lane = tid & 63;
  int pbase = blockIdx.x * 64 + wave * 8;
  const float4* x4 = (const float4*)x;

  // x_norm for the wave's 8 points: lane-parallel coalesced read + butterfly
  float xn[8];
#pragma unroll
  for (int i = 0; i < 8; i++) {
    float4 xv = x4[(size_t)(pbase + i) * 64 + lane];
    float s = fmaf(xv.x, xv.x, fmaf(xv.y, xv.y, fmaf(xv.z, xv.z, xv.w * xv.w)));
#pragma unroll
    for (int m = 1; m < 64; m <<= 1) s += __shfl_xor(s, m);
    xn[i] = s;
  }

  float acc[8] = {0.f,0.f,0.f,0.f,0.f,0.f,0.f,0.f};
  float yn = 0.0f;
  size_t xbase = (size_t)pbase * 64;
#pragma unroll 2
  for (int j = 0; j < 64; j++) {
    float4 c = cbT[(j << 6) | (lane ^ j)];
    yn = fmaf(c.x, c.x, fmaf(c.y, c.y, fmaf(c.z, c.z, fmaf(c.w, c.w, yn))));
#pragma unroll
    for (int i = 0; i < 8; i++) {
      float4 xv = x4[xbase + (size_t)i * 64 + j];  // wave-uniform broadcast load
      acc[i] = fmaf(xv.x, c.x, fmaf(xv.y, c.y, fmaf(xv.z, c.z, fmaf(xv.w, c.w, acc[i]))));
    }
  }

  int* nnzp = (int*)(ws + OFF_NNZ);
  int* rowidx = (int*)(ws + OFF_ROWIDX);
  int* rowseg = (int*)(ws + OFF_ROWSEG);
  float* krows = ws + OFF_KROWS;

#pragma unroll
  for (int i = 0; i < 8; i++) {
    int p = pbase + i;
    float cost = fmaxf(xn[i] + yn - 2.0f * acc[i], 0.0f);
    float km = __expf(cost * (-1.0f / EPSV));
    if (!(km <= 1.0f)) km = STABV;  // NaN/Inf -> STAB (mirrors reference where())
    unsigned long long nz = __ballot(km != 0.0f);
    if (nz != 0ull) {               // row contributes; compact it (exact: zero rows add 0)
      int slot = 0;
      if (lane == 0) slot = atomicAdd(nnzp, 1);
      slot = __shfl(slot, 0);
      if (slot < cap) {
        krows[(size_t)slot * 64 + lane] = km;
        if (lane == 0) { rowidx[slot] = p; rowseg[slot] = bidx[p >> 3]; }
      }
    }
  }
}

// Single block runs all 20 Sinkhorn iterations over the compacted rows plus the
// epilogue. General-correct for any nnz (grid-strided waves); near-free when the
// compact set is empty.
__global__ __launch_bounds__(256) void solve_kernel(float* __restrict__ ws,
                                                    float* __restrict__ out, int cap) {
  __shared__ float vsh[NG * KK];
  __shared__ float ash[NG * KK];
  __shared__ float tot[NG];
  int tid = threadIdx.x;
  int wave = tid >> 6, lane = tid & 63;
  int nnz = ((int*)(ws + OFF_NNZ))[0];
  if (nnz > cap) nnz = cap;
  const float* krows = ws + OFF_KROWS;
  const int* rowseg = (const int*)(ws + OFF_ROWSEG);
  const int* counts = (const int*)(ws + OFF_COUNTS);
  float* uc = ws + OFF_UC;

  for (int i = tid; i < NG * KK; i += 256) vsh[i] = 1.0f;  // v0 = 1
  __syncthreads();

  for (int it = 0; it < NITERS; it++) {
    for (int i = tid; i < NG * KK; i += 256) ash[i] = 0.0f;  // KTu accum
    __syncthreads();
    for (int r = wave; r < nnz; r += 4) {
      int g = rowseg[r];
      float kw = krows[(size_t)r * 64 + lane];
      float kv = kw * vsh[(g << 6) | lane];
#pragma unroll
      for (int m = 1; m < 64; m <<= 1) kv += __shfl_xor(kv, m);
      float u = ws[OFF_AINV + g] / fmaxf(kv, STABV);
      if (it == NITERS - 1 && lane == 0) uc[r] = u;
      atomicAdd(&ash[(g << 6) | lane], kw * u);
    }
    __syncthreads();
    for (int i = tid; i < NG * KK; i += 256)
      vsh[i] = (1.0f / KK) / fmaxf(ash[i], STABV);
    __syncthreads();
  }

  // wsum = segsum(K * clip(u)) * clip(v); normalize per graph
  for (int i = tid; i < NG * KK; i += 256) ash[i] = 0.0f;
  __syncthreads();
  for (int r = wave; r < nnz; r += 4) {
    int g = rowseg[r];
    float kw = krows[(size_t)r * 64 + lane];
    float u = fminf(fmaxf(uc[r], STABV), CMAXV);
    atomicAdd(&ash[(g << 6) | lane], kw * u);
  }
  __syncthreads();
  for (int i = tid; i < NG * KK; i += 256) {
    float vv = fminf(fmaxf(vsh[i], STABV), CMAXV);
    ash[i] = ash[i] * vv;
  }
  __syncthreads();
  if (tid < NG) {
    float s = 0.0f;
    for (int k = 0; k < KK; k++) s += ash[(tid << 6) + k];
    tot[tid] = s;
  }
  __syncthreads();
  for (int i = tid; i < NG * KK; i += 256) {
    int g = i >> 6;
    float val;
    if (counts[g] == 0) val = 0.0f;
    else if (tot[g] > STABV) val = ash[i] / fmaxf(tot[g], STABV);
    else val = 1.0f / KK;
    out[i] = val;
  }
}

extern "C" void kernel_launch(void* const* d_in, const int* in_sizes, int n_in,
                              void* d_out, int out_size, void* d_ws, size_t ws_size,
                              hipStream_t stream) {
  const float* x = (const float*)d_in[0];      // [50000,8,256] f32
  const int* bidx = (const int*)d_in[1];       // [50000] int
  const float* cb = (const float*)d_in[2];     // [64,256] f32
  float* ws = (float*)d_ws;
  float* out = (float*)d_out;

  long cap_l = ((long)(ws_size / 4) - OFF_KROWS) / 64;
  if (cap_l < 0) cap_l = 0;
  if (cap_l > PTOT) cap_l = PTOT;
  int cap = (int)cap_l;

  init_kernel<<<1, 256, 0, stream>>>(ws);
  counts_kernel<<<(NNODES + 255) / 256, 256, 0, stream>>>(bidx, ws);
  ainv_kernel<<<1, 64, 0, stream>>>(ws);
  cost_kernel<<<PTOT / 64, 512, 0, stream>>>(x, bidx, cb, ws, cap);
  solve_kernel<<<1, 256, 0, stream>>>(ws, out, cap);
}

// Round 2
// 571.152 us; speedup vs baseline: 2.1118x; 2.1118x over previous
//
#include <hip/hip_runtime.h>

#define NG 64
#define KK 64
#define HIDDEN 256
#define DIST 8
#define NNODES 50000
#define PTOT (NNODES*DIST)   // 400000 flattened rows
#define EPSV 0.1f
#define NITERS 20
#define STABV 1e-8f
#define CMAXV 1e6f

// Cauchy-Schwarz underflow certificate: cost >= (||x||-||y||)^2 exactly.
// expf(-t)==0.0f for t>~104; cost/EPS>104 <=> cost>10.4. Require bound>64
// (6x margin over the underflow threshold; actual data gives >~120).
#define CERT_COST 64.0f

// workspace layout (float-element offsets)
#define OFF_AINV 0                       // 64 f32: 1/max(rows_per_graph,1)
#define OFF_COUNTS 64                    // 64 i32: nodes per graph
#define OFF_NNZ 128                      // 1 i32: nonzero Kmat rows found
#define OFF_NSUS 129                     // 1 i32: suspect points found
#define OFF_MAXY 130                     // 1 f32: max_k ||y_k||
#define OFF_YN 192                       // 64 f32: ||y_k||^2
#define OFF_SUS 256                      // PTOT i32: suspect point ids
#define OFF_ROWSEG (OFF_SUS + PTOT)      // PTOT i32: graph id per compact row
#define OFF_UC (OFF_ROWSEG + PTOT)       // PTOT f32: final u per compact row
#define OFF_KROWS (OFF_UC + PTOT)        // cap*64 f32: compacted Kmat rows

__global__ __launch_bounds__(256) void init_kernel(float* ws) {
  int t = threadIdx.x;
  if (t == 0) { ((int*)(ws + OFF_NNZ))[0] = 0; ((int*)(ws + OFF_NSUS))[0] = 0; }
  if (t < NG) ((int*)(ws + OFF_COUNTS))[t] = 0;
}

__global__ __launch_bounds__(256) void counts_kernel(const int* __restrict__ bidx,
                                                     float* ws) {
  __shared__ int h[NG];
  int t = threadIdx.x;
  if (t < NG) h[t] = 0;
  __syncthreads();
  int i = blockIdx.x * 256 + t;
  if (i < NNODES) atomicAdd(&h[bidx[i]], 1);
  __syncthreads();
  if (t < NG && h[t] > 0) atomicAdd(&((int*)(ws + OFF_COUNTS))[t], h[t]);
}

__global__ __launch_bounds__(64) void ainv_kernel(float* ws) {
  int g = threadIdx.x;
  int c = ((int*)(ws + OFF_COUNTS))[g];
  ws[OFF_AINV + g] = 1.0f / fmaxf((float)(c * DIST), 1.0f);
}

// One wave: lane k computes ||y_k||^2 and the wave max of ||y_k||.
__global__ __launch_bounds__(64) void cbnorm_kernel(const float* __restrict__ cb,
                                                    float* ws) {
  int lane = threadIdx.x;
  const float4* cb4 = (const float4*)cb;
  float yn = 0.0f;
  for (int j = 0; j < 64; j++) {
    float4 c = cb4[lane * 64 + j];
    yn = fmaf(c.x, c.x, fmaf(c.y, c.y, fmaf(c.z, c.z, fmaf(c.w, c.w, yn))));
  }
  ws[OFF_YN + lane] = yn;
  float ymax = sqrtf(yn);
#pragma unroll
  for (int m = 1; m < 64; m <<= 1) ymax = fmaxf(ymax, __shfl_xor(ymax, m));
  if (lane == 0) ws[OFF_MAXY] = ymax;
}

// Streaming pass: wave handles 8 points (1 coalesced float4 load per point per
// lane = exactly the point's 1 KB). Butterfly-reduce ||x||^2; apply the
// Cauchy-Schwarz certificate; points failing it go to the suspect list.
__global__ __launch_bounds__(256) void norm_suspect_kernel(const float* __restrict__ x,
                                                           float* __restrict__ ws) {
  int tid = threadIdx.x;
  int wave = tid >> 6, lane = tid & 63;
  size_t pbase = (size_t)blockIdx.x * 32 + (size_t)wave * 8;
  const float4* x4 = (const float4*)x;
  float maxy = ws[OFF_MAXY];  // wave-uniform scalar load

  float4 xv[8];
#pragma unroll
  for (int i = 0; i < 8; i++) xv[i] = x4[(pbase + i) * 64 + lane];
  float s[8];
#pragma unroll
  for (int i = 0; i < 8; i++)
    s[i] = fmaf(xv[i].x, xv[i].x, fmaf(xv[i].y, xv[i].y,
           fmaf(xv[i].z, xv[i].z, xv[i].w * xv[i].w)));
#pragma unroll
  for (int m = 1; m < 64; m <<= 1) {
#pragma unroll
    for (int i = 0; i < 8; i++) s[i] += __shfl_xor(s[i], m);
  }
  // lane l (l<8) owns point pbase+l
  float mine = 0.0f;
#pragma unroll
  for (int i = 0; i < 8; i++) if (lane == i) mine = s[i];
  if (lane < 8) {
    float r = sqrtf(mine) - maxy;
    bool safe = (mine < 1e30f) && (r > 0.0f) && (r * r > CERT_COST);  // NaN -> !safe
    if (!safe) {
      int slot = atomicAdd((int*)(ws + OFF_NSUS), 1);
      if (slot < PTOT) ((int*)(ws + OFF_SUS))[slot] = (int)(pbase + lane);
    }
  }
}

// Exact fallback for suspect points: full reference-semantics Kmat row.
// Fixed grid, grid-strided; near-free when the suspect list is empty.
__global__ __launch_bounds__(256) void suspect_kernel(const float* __restrict__ x,
    const int* __restrict__ bidx, const float* __restrict__ cb,
    float* __restrict__ ws, int cap) {
  int tid = threadIdx.x;
  int wave = tid >> 6, lane = tid & 63;
  int nsus = ((int*)(ws + OFF_NSUS))[0];
  if (nsus > PTOT) nsus = PTOT;
  const int* sus = (const int*)(ws + OFF_SUS);
  const float4* x4 = (const float4*)x;
  const float4* cb4 = (const float4*)cb;
  int gw = blockIdx.x * 4 + wave, nw = gridDim.x * 4;
  for (int si = gw; si < nsus; si += nw) {
    int p = sus[si];
    float4 xv = x4[(size_t)p * 64 + lane];
    float xn = fmaf(xv.x, xv.x, fmaf(xv.y, xv.y, fmaf(xv.z, xv.z, xv.w * xv.w)));
#pragma unroll
    for (int m = 1; m < 64; m <<= 1) xn += __shfl_xor(xn, m);
    float myk = 0.0f;
    for (int k = 0; k < 64; k++) {
      float4 c = cb4[k * 64 + lane];
      float d = fmaf(xv.x, c.x, fmaf(xv.y, c.y, fmaf(xv.z, c.z, xv.w * c.w)));
#pragma unroll
      for (int m = 1; m < 64; m <<= 1) d += __shfl_xor(d, m);
      float cost = fmaxf(xn + ws[OFF_YN + k] - 2.0f * d, 0.0f);
      float km = __expf(cost * (-1.0f / EPSV));
      if (!(km <= 1.0f)) km = STABV;  // NaN/Inf -> STAB, per reference
      if (lane == k) myk = km;
    }
    unsigned long long nz = __ballot(myk != 0.0f);
    if (nz != 0ull) {
      int slot = 0;
      if (lane == 0) slot = atomicAdd((int*)(ws + OFF_NNZ), 1);
      slot = __shfl(slot, 0);
      if (slot < cap) {
        (ws + OFF_KROWS)[(size_t)slot * 64 + lane] = myk;
        if (lane == 0) ((int*)(ws + OFF_ROWSEG))[slot] = bidx[p >> 3];
      }
    }
  }
}

// Single block runs all 20 Sinkhorn iterations over the compacted rows plus the
// epilogue. General-correct for any nnz; near-free when the compact set is empty.
__global__ __launch_bounds__(256) void solve_kernel(float* __restrict__ ws,
                                                    float* __restrict__ out, int cap) {
  __shared__ float vsh[NG * KK];
  __shared__ float ash[NG * KK];
  __shared__ float tot[NG];
  int tid = threadIdx.x;
  int wave = tid >> 6, lane = tid & 63;
  int nnz = ((int*)(ws + OFF_NNZ))[0];
  if (nnz > cap) nnz = cap;
  const float* krows = ws + OFF_KROWS;
  const int* rowseg = (const int*)(ws + OFF_ROWSEG);
  const int* counts = (const int*)(ws + OFF_COUNTS);
  float* uc = ws + OFF_UC;

  for (int i = tid; i < NG * KK; i += 256) vsh[i] = 1.0f;  // v0 = 1
  __syncthreads();

  for (int it = 0; it < NITERS; it++) {
    for (int i = tid; i < NG * KK; i += 256) ash[i] = 0.0f;  // KTu accum
    __syncthreads();
    for (int r = wave; r < nnz; r += 4) {
      int g = rowseg[r];
      float kw = krows[(size_t)r * 64 + lane];
      float kv = kw * vsh[(g << 6) | lane];
#pragma unroll
      for (int m = 1; m < 64; m <<= 1) kv += __shfl_xor(kv, m);
      float u = ws[OFF_AINV + g] / fmaxf(kv, STABV);
      if (it == NITERS - 1 && lane == 0) uc[r] = u;
      atomicAdd(&ash[(g << 6) | lane], kw * u);
    }
    __syncthreads();
    for (int i = tid; i < NG * KK; i += 256)
      vsh[i] = (1.0f / KK) / fmaxf(ash[i], STABV);
    __syncthreads();
  }

  // wsum = segsum(K * clip(u)) * clip(v); normalize per graph
  for (int i = tid; i < NG * KK; i += 256) ash[i] = 0.0f;
  __syncthreads();
  for (int r = wave; r < nnz; r += 4) {
    int g = rowseg[r];
    float kw = krows[(size_t)r * 64 + lane];
    float u = fminf(fmaxf(uc[r], STABV), CMAXV);
    atomicAdd(&ash[(g << 6) | lane], kw * u);
  }
  __syncthreads();
  for (int i = tid; i < NG * KK; i += 256) {
    float vv = fminf(fmaxf(vsh[i], STABV), CMAXV);
    ash[i] = ash[i] * vv;
  }
  __syncthreads();
  if (tid < NG) {
    float s = 0.0f;
    for (int k = 0; k < KK; k++) s += ash[(tid << 6) + k];
    tot[tid] = s;
  }
  __syncthreads();
  for (int i = tid; i < NG * KK; i += 256) {
    int g = i >> 6;
    float val;
    if (counts[g] == 0) val = 0.0f;
    else if (tot[g] > STABV) val = ash[i] / fmaxf(tot[g], STABV);
    else val = 1.0f / KK;
    out[i] = val;
  }
}

extern "C" void kernel_launch(void* const* d_in, const int* in_sizes, int n_in,
                              void* d_out, int out_size, void* d_ws, size_t ws_size,
                              hipStream_t stream) {
  const float* x = (const float*)d_in[0];      // [50000,8,256] f32
  const int* bidx = (const int*)d_in[1];       // [50000] int
  const float* cb = (const float*)d_in[2];     // [64,256] f32
  float* ws = (float*)d_ws;
  float* out = (float*)d_out;

  long cap_l = ((long)(ws_size / 4) - OFF_KROWS) / 64;
  if (cap_l < 0) cap_l = 0;
  if (cap_l > PTOT) cap_l = PTOT;
  int cap = (int)cap_l;

  init_kernel<<<1, 256, 0, stream>>>(ws);
  counts_kernel<<<(NNODES + 255) / 256, 256, 0, stream>>>(bidx, ws);
  ainv_kernel<<<1, 64, 0, stream>>>(ws);
  cbnorm_kernel<<<1, 64, 0, stream>>>(cb, ws);
  norm_suspect_kernel<<<PTOT / 32, 256, 0, stream>>>(x, ws);
  suspect_kernel<<<64, 256, 0, stream>>>(x, bidx, cb, ws, cap);
  solve_kernel<<<1, 256, 0, stream>>>(ws, out, cap);
}

// Round 3
// 479.220 us; speedup vs baseline: 2.5169x; 1.1918x over previous
//
#include <hip/hip_runtime.h>

#define NG 64
#define KK 64
#define DIST 8
#define NNODES 50000
#define PTOT (NNODES*DIST)   // 400000 flattened rows
#define EPSV 0.1f
#define NITERS 20
#define STABV 1e-8f
#define CMAXV 1e6f

// ws layout (float-element offsets). ws is poisoned 0xAA before every call;
// everything below is written before it is read.
#define OFF_COUNTS 0                    // 64 i32
#define OFF_NNZ 64                      // 1 i32
#define OFF_NSUS 65                     // 1 i32
#define OFF_MAXY 66                     // 1 f32
#define OFF_YN 128                      // 64 f32
#define OFF_SUS 192                     // PTOT i32
#define OFF_ROWSEG (OFF_SUS + PTOT)     // PTOT i32
#define OFF_UC (OFF_ROWSEG + PTOT)      // PTOT f32
#define OFF_KROWS (OFF_UC + PTOT)       // cap*64 f32

__device__ __forceinline__ float dot4(float4 a, float4 b) {
  return fmaf(a.x, b.x, fmaf(a.y, b.y, fmaf(a.z, b.z, a.w * b.w)));
}

// Zero counters + codebook norms. Wave w, iter it exclusively owns k=4*it+w:
// coalesced cb read, butterfly reduce, no atomics.
__global__ __launch_bounds__(256) void init_kernel(const float* __restrict__ cb,
                                                   float* __restrict__ ws) {
  __shared__ float ynsh[KK];
  int t = threadIdx.x, w = t >> 6, l = t & 63;
  if (t < NG) ((int*)ws)[OFF_COUNTS + t] = 0;
  if (t == 0) { ((int*)ws)[OFF_NNZ] = 0; ((int*)ws)[OFF_NSUS] = 0; }
  const float4* cb4 = (const float4*)cb;
#pragma unroll
  for (int it = 0; it < 16; it++) {
    float4 c = cb4[it * 256 + t];
    float e = dot4(c, c);
#pragma unroll
    for (int m = 1; m < 64; m <<= 1) e += __shfl_xor(e, m);
    if (l == 0) ynsh[it * 4 + w] = e;
  }
  __syncthreads();
  if (t < KK) {
    float yn = ynsh[t];
    ws[OFF_YN + t] = yn;
    float ym = sqrtf(yn);
#pragma unroll
    for (int m = 1; m < 64; m <<= 1) ym = fmaxf(ym, __shfl_xor(ym, m));
    if (t == 0) ws[OFF_MAXY] = ym;
  }
}

// Fused counts + subset-norm certificate pass.
// Certificate (exact math, no approximation): for ANY coordinate subset,
// S = sum x_i^2 <= ||x||^2, so cost(p,k) >= (sqrt(S) - max_k||y_k||)^2.
// fp32 exp(-cost/0.1) == 0.0 exactly whenever cost > 10.41; we demand
// certified cost > 12.96 (slack >> fp32 rounding of the reference's cost).
// Points failing the cert go to the exact fallback (reference semantics).
// Subset = first 64 of 256 elems = first 256B = two full 128B lines/point.
__global__ __launch_bounds__(256) void main_kernel(const float* __restrict__ x,
    const int* __restrict__ bidx, float* __restrict__ ws) {
  __shared__ int hist[NG];
  int t = threadIdx.x, w = t >> 6, l = t & 63;
  int b = blockIdx.x;
  // --- per-graph node counts (this block's 40-node slice) ---
  if (t < NG) hist[t] = 0;
  __syncthreads();
  if (t < 40) atomicAdd(&hist[bidx[b * 40 + t] & 63], 1);
  __syncthreads();
  if (t < NG && hist[t] > 0) atomicAdd(&((int*)ws)[OFF_COUNTS + t], hist[t]);

  // --- subset-norm certificate, 320 points/block, 80/wave ---
  float maxy = ws[OFF_MAXY];
  float thr = fmaf(maxy, 1.0001f, 0.01f) + 3.6f;  // 3.6^2 = 12.96 > 10.41
  float thr2 = thr * thr;
  const float4* x4 = (const float4*)x;
  int q = l >> 4, r = l & 15;  // 16-lane group q reads f4 0..15 of its point
  int base = b * 320 + w * 80;
  int* nsusp = &((int*)ws)[OFF_NSUS];
  int* sus = &((int*)ws)[OFF_SUS];
#pragma unroll
  for (int o = 0; o < 5; o++) {
    int p0 = base + o * 16;
    float4 v0 = x4[(size_t)(p0 + q) * 64 + r];
    float4 v1 = x4[(size_t)(p0 + 4 + q) * 64 + r];
    float4 v2 = x4[(size_t)(p0 + 8 + q) * 64 + r];
    float4 v3 = x4[(size_t)(p0 + 12 + q) * 64 + r];
    float s0 = dot4(v0, v0), s1 = dot4(v1, v1), s2 = dot4(v2, v2), s3 = dot4(v3, v3);
#pragma unroll
    for (int m = 1; m < 16; m <<= 1) {
      s0 += __shfl_xor(s0, m); s1 += __shfl_xor(s1, m);
      s2 += __shfl_xor(s2, m); s3 += __shfl_xor(s3, m);
    }
    if (r == 0) {  // lane 16*q owns points p0+q, p0+4+q, p0+8+q, p0+12+q
      float ss[4] = {s0, s1, s2, s3};
#pragma unroll
      for (int i = 0; i < 4; i++) {
        // NaN in subset -> comparison false -> suspect. Inf -> >1e30 -> suspect.
        bool safe = (ss[i] > thr2) && (ss[i] < 1e30f);
        if (!safe) {
          int slot = atomicAdd(nsusp, 1);
          if (slot < PTOT) sus[slot] = p0 + 4 * i + q;
        }
      }
    }
  }
}

// Exact fallback: full reference-semantics Kmat row for each suspect point;
// nonzero rows are compacted for the solver. Grid-strided; near-free when empty.
__global__ __launch_bounds__(256) void suspect_kernel(const float* __restrict__ x,
    const int* __restrict__ bidx, float* __restrict__ ws, int cap) {
  int tid = threadIdx.x;
  int wave = tid >> 6, lane = tid & 63;
  int nsus = ((int*)ws)[OFF_NSUS];
  if (nsus > PTOT) nsus = PTOT;
  const int* sus = &((int*)ws)[OFF_SUS];
  const float4* x4 = (const float4*)x;
  int gw = blockIdx.x * 4 + wave, nw = gridDim.x * 4;
  for (int si = gw; si < nsus; si += nw) {
    int p = sus[si];
    float4 xv = x4[(size_t)p * 64 + lane];
    float xn = dot4(xv, xv);
#pragma unroll
    for (int m = 1; m < 64; m <<= 1) xn += __shfl_xor(xn, m);
    float myk = 0.0f;
    for (int k = 0; k < KK; k++) {
      // recompute codebook row k dot x (cb re-derived from ws yn + cb in L2 is
      // not available here; read cb via x? No: we stored only norms, so read
      // codebook directly from its global buffer -- passed via ws? Simplest:
      // codebook pointer is passed separately below.
      k = k;  // placeholder (real loop body below in cb-version)
    }
    (void)myk; (void)xn;
  }
}

// NOTE: suspect_kernel above replaced by cb-aware version:
__global__ __launch_bounds__(256) void suspect2_kernel(const float* __restrict__ x,
    const int* __restrict__ bidx, const float* __restrict__ cb,
    float* __restrict__ ws, int cap) {
  int tid = threadIdx.x;
  int wave = tid >> 6, lane = tid & 63;
  int nsus = ((int*)ws)[OFF_NSUS];
  if (nsus > PTOT) nsus = PTOT;
  const int* sus = &((int*)ws)[OFF_SUS];
  const float4* x4 = (const float4*)x;
  const float4* cb4 = (const float4*)cb;
  int gw = blockIdx.x * 4 + wave, nw = gridDim.x * 4;
  for (int si = gw; si < nsus; si += nw) {
    int p = sus[si];
    float4 xv = x4[(size_t)p * 64 + lane];
    float xn = dot4(xv, xv);
#pragma unroll
    for (int m = 1; m < 64; m <<= 1) xn += __shfl_xor(xn, m);
    float myk = 0.0f;
    for (int k = 0; k < KK; k++) {
      float4 c = cb4[k * 64 + lane];
      float d = dot4(xv, c);
#pragma unroll
      for (int m = 1; m < 64; m <<= 1) d += __shfl_xor(d, m);
      float cost = fmaxf(xn + ws[OFF_YN + k] - 2.0f * d, 0.0f);
      float km = __expf(cost * (-1.0f / EPSV));
      if (!(km <= 1.0f)) km = STABV;  // NaN/Inf -> STAB, per reference
      if (lane == k) myk = km;
    }
    unsigned long long nz = __ballot(myk != 0.0f);
    if (nz != 0ull) {
      int slot = 0;
      if (lane == 0) slot = atomicAdd(&((int*)ws)[OFF_NNZ], 1);
      slot = __shfl(slot, 0);
      if (slot < cap) {
        (ws + OFF_KROWS)[(size_t)slot * 64 + lane] = myk;
        if (lane == 0) ((int*)ws)[OFF_ROWSEG + slot] = bidx[p >> 3];
      }
    }
  }
}

// Sinkhorn over compacted rows + epilogue. Skips the 20-iter loop when the
// compact set is empty (device-side branch; launch sequence is unchanged).
__global__ __launch_bounds__(256) void solve_kernel(float* __restrict__ ws,
                                                    float* __restrict__ out, int cap) {
  __shared__ float vsh[NG * KK];
  __shared__ float ash[NG * KK];
  __shared__ float tot[NG];
  __shared__ float ainv[NG];
  int tid = threadIdx.x;
  int wave = tid >> 6, lane = tid & 63;
  int nnz = ((int*)ws)[OFF_NNZ];
  if (nnz > cap) nnz = cap;
  const float* krows = ws + OFF_KROWS;
  const int* rowseg = &((int*)ws)[OFF_ROWSEG];
  const int* counts = &((int*)ws)[OFF_COUNTS];
  float* uc = ws + OFF_UC;

  if (tid < NG) ainv[tid] = 1.0f / fmaxf((float)(counts[tid] * DIST), 1.0f);
  for (int i = tid; i < NG * KK; i += 256) { vsh[i] = 1.0f; ash[i] = 0.0f; }
  __syncthreads();

  if (nnz > 0) {
    for (int it = 0; it < NITERS; it++) {
      for (int i = tid; i < NG * KK; i += 256) ash[i] = 0.0f;
      __syncthreads();
      for (int r = wave; r < nnz; r += 4) {
        int g = rowseg[r];
        float kw = krows[(size_t)r * 64 + lane];
        float kv = kw * vsh[(g << 6) | lane];
#pragma unroll
        for (int m = 1; m < 64; m <<= 1) kv += __shfl_xor(kv, m);
        float u = ainv[g] / fmaxf(kv, STABV);
        if (it == NITERS - 1 && lane == 0) uc[r] = u;
        atomicAdd(&ash[(g << 6) | lane], kw * u);
      }
      __syncthreads();
      for (int i = tid; i < NG * KK; i += 256)
        vsh[i] = (1.0f / KK) / fmaxf(ash[i], STABV);
      __syncthreads();
    }
    for (int i = tid; i < NG * KK; i += 256) ash[i] = 0.0f;
    __syncthreads();
    for (int r = wave; r < nnz; r += 4) {
      int g = rowseg[r];
      float kw = krows[(size_t)r * 64 + lane];
      float u = fminf(fmaxf(uc[r], STABV), CMAXV);
      atomicAdd(&ash[(g << 6) | lane], kw * u);
    }
    __syncthreads();
  }

  for (int i = tid; i < NG * KK; i += 256) {
    float vv = fminf(fmaxf(vsh[i], STABV), CMAXV);
    ash[i] = ash[i] * vv;
  }
  __syncthreads();
  if (tid < NG) {
    float s = 0.0f;
    for (int k = 0; k < KK; k++) s += ash[(tid << 6) + k];
    tot[tid] = s;
  }
  __syncthreads();
  for (int i = tid; i < NG * KK; i += 256) {
    int g = i >> 6;
    float val;
    if (counts[g] == 0) val = 0.0f;
    else if (tot[g] > STABV) val = ash[i] / fmaxf(tot[g], STABV);
    else val = 1.0f / KK;
    out[i] = val;
  }
}

extern "C" void kernel_launch(void* const* d_in, const int* in_sizes, int n_in,
                              void* d_out, int out_size, void* d_ws, size_t ws_size,
                              hipStream_t stream) {
  const float* x = (const float*)d_in[0];      // [50000,8,256] f32
  const int* bidx = (const int*)d_in[1];       // [50000] int32
  const float* cb = (const float*)d_in[2];     // [64,256] f32
  float* ws = (float*)d_ws;
  float* out = (float*)d_out;

  long cap_l = ((long)(ws_size / 4) - OFF_KROWS) / 64;
  if (cap_l < 0) cap_l = 0;
  if (cap_l > PTOT) cap_l = PTOT;
  int cap = (int)cap_l;

  init_kernel<<<1, 256, 0, stream>>>(cb, ws);
  main_kernel<<<NNODES / 40, 256, 0, stream>>>(x, bidx, ws);  // 1250 blocks
  suspect2_kernel<<<64, 256, 0, stream>>>(x, bidx, cb, ws, cap);
  solve_kernel<<<1, 256, 0, stream>>>(ws, out, cap);
}